// Round 3
// baseline (799.466 us; speedup 1.0000x reference)
//
#include <hip/hip_runtime.h>
#include <cstddef>

// Problem constants
#define B_   4
#define NS_  96
#define T_   8
#define H_   256
#define N_   97      // NS + 1
#define NL_  6       // NUM_LAYERS

__device__ __forceinline__ float sigm(float x) { return 1.0f / (1.0f + expf(-x)); }

// ---------------- generic: C[m,n] = sum_k A[m,k]*B[k,n] (+bias[n]), K<=256 ----------------
__global__ void gemm_rowwise(const float* __restrict__ A, const float* __restrict__ Bm,
                             const float* __restrict__ bias, float* __restrict__ C,
                             int K, int Nc) {
    __shared__ float a[256];
    int m = blockIdx.y;
    int t = threadIdx.x;
    if (t < K) a[t] = A[m * K + t];
    __syncthreads();
    int n = blockIdx.x * 256 + t;
    if (n < Nc) {
        float acc = bias ? bias[n] : 0.0f;
        for (int k = 0; k < K; k++) acc = fmaf(a[k], Bm[k * Nc + n], acc);
        C[m * Nc + n] = acc;
    }
}

// ---------------- xz = embed[ids] @ Wx_s + b_s   [3072,1024], 8 rows/block ----------------
__global__ void xz_gemm(const int* __restrict__ ids, const float* __restrict__ embed,
                        const float* __restrict__ Wx, const float* __restrict__ bs,
                        float* __restrict__ xz) {
    __shared__ float x[8][H_];
    __shared__ int idx[8];
    int t = threadIdx.x;             // 0..1023
    int r0 = blockIdx.x * 8;
    if (t < 8) idx[t] = ids[r0 + t];
    __syncthreads();
    {
        int r = t >> 7;              // 0..7
        int cb = (t & 127) * 2;
        const float* e = embed + (size_t)idx[r] * H_;
        x[r][cb] = e[cb];
        x[r][cb + 1] = e[cb + 1];
    }
    __syncthreads();
    float acc[8];
    float bv = bs[t];
#pragma unroll
    for (int r = 0; r < 8; r++) acc[r] = bv;
#pragma unroll 4
    for (int k = 0; k < H_; k++) {
        float wv = Wx[k * 1024 + t];
#pragma unroll
        for (int r = 0; r < 8; r++) acc[r] = fmaf(x[r][k], wv, acc[r]);
    }
#pragma unroll
    for (int r = 0; r < 8; r++) xz[(size_t)(r0 + r) * 1024 + t] = acc[r];
}

// ---------------- recurrent LSTM over precomputed xz, 2 seqs/block, 1024 thr ----------------
__global__ void lstm_rec(const float* __restrict__ xz, const float* __restrict__ Wh,
                         float* __restrict__ stmt) {
    __shared__ float hb[2][H_];
    __shared__ float zb[2][1024];
    int t = threadIdx.x;             // 0..1023
    int s0 = blockIdx.x * 2;
    float c[2] = {0.0f, 0.0f};
    for (int step = 0; step < T_; step++) {
        float a0 = xz[(((size_t)s0) * T_ + step) * 1024 + t];
        float a1 = xz[(((size_t)s0 + 1) * T_ + step) * 1024 + t];
        if (step > 0) {              // h == 0 at step 0
#pragma unroll 4
            for (int k = 0; k < H_; k++) {
                float wv = Wh[k * 1024 + t];
                a0 = fmaf(hb[0][k], wv, a0);
                a1 = fmaf(hb[1][k], wv, a1);
            }
        }
        zb[0][t] = a0;
        zb[1][t] = a1;
        __syncthreads();
        if (t < H_) {
#pragma unroll
            for (int s = 0; s < 2; s++) {
                float gi = zb[s][t], gf = zb[s][256 + t], gg = zb[s][512 + t], go = zb[s][768 + t];
                c[s] = sigm(gf) * c[s] + sigm(gi) * tanhf(gg);
                hb[s][t] = sigm(go) * tanhf(c[s]);
            }
        }
        __syncthreads();
    }
    if (t < H_) {
        stmt[(size_t)s0 * H_ + t] = hb[0][t];
        stmt[((size_t)s0 + 1) * H_ + t] = hb[1][t];
    }
}

// ---------------- prefix sums over statements ----------------
__global__ void cumsum_k(const float* __restrict__ stmt, float* __restrict__ pref) {
    int b = blockIdx.x, t = threadIdx.x;
    float run = 0.0f;
    pref[((size_t)b * N_) * H_ + t] = 0.0f;
    for (int n = 1; n < N_; n++) {
        run += stmt[((size_t)b * NS_ + n - 1) * H_ + t];
        pref[((size_t)b * N_ + n) * H_ + t] = run;
    }
}

// ---------------- q = pref@M1 (4H), r = pref@M2 (H) + rT; 1 row/block, 1024 thr ----------------
__global__ void qr_gemm(const float* __restrict__ pref, const float* __restrict__ M1,
                        const float* __restrict__ M2, float* __restrict__ q,
                        float* __restrict__ r, float* __restrict__ rT) {
    __shared__ float pf[H_];
    int t = threadIdx.x;             // 0..1023
    int row = blockIdx.x;            // 0..387
    if (t < H_) pf[t] = pref[(size_t)row * H_ + t];
    __syncthreads();
    float aq = 0.0f, ar = 0.0f;
#pragma unroll 4
    for (int k = 0; k < H_; k++) {
        float pv = pf[k];
        aq = fmaf(pv, M1[k * 1024 + t], aq);
        if (t < H_) ar = fmaf(pv, M2[k * 256 + t], ar);
    }
    q[(size_t)row * 1024 + t] = aq;
    if (t < H_) {
        r[(size_t)row * H_ + t] = ar;
        int b = row / N_, n = row % N_;
        rT[((size_t)b * H_ + t) * 128 + n] = ar;
    }
}

// ---------------- init c/h/p ----------------
__global__ void init_state(const float* __restrict__ ia, const float* __restrict__ ib,
                           float* __restrict__ c0, float* __restrict__ h0,
                           float* __restrict__ p0) {
    int row = blockIdx.x, t = threadIdx.x;
    size_t idx = (size_t)row * H_ + t;
    c0[idx] = ia[t];
    h0[idx] = ib[t];
    if (t == 0) p0[row] = ((row % N_) == 0) ? 1.0f : 0.0f;
}

// ---------------- per-layer: he = h@Wh_e + cz ; hterm row-scalar; 1 row/block, 1024 thr ----------------
__global__ void hproj(const float* __restrict__ h, const float* __restrict__ Whe,
                      const float* __restrict__ Whk, const float* __restrict__ bhk,
                      const float* __restrict__ Wd1, const float* __restrict__ cz,
                      float* __restrict__ he, float* __restrict__ hterm) {
    __shared__ float hr[H_];
    __shared__ float red[H_];
    int t = threadIdx.x;             // 0..1023
    int row = blockIdx.x;            // 0..387
    if (t < H_) hr[t] = h[(size_t)row * H_ + t];
    __syncthreads();
    float ae = cz[t];
    float ak = 0.0f;
#pragma unroll 4
    for (int k = 0; k < H_; k++) {
        float hv = hr[k];
        ae = fmaf(hv, Whe[k * 1024 + t], ae);
        if (t < H_) ak = fmaf(hv, Whk[k * 256 + t], ak);
    }
    he[(size_t)row * 1024 + t] = ae;
    if (t < H_) red[t] = fmaxf(ak + bhk[t], 0.0f) * Wd1[t];
    __syncthreads();
    for (int off = 128; off > 0; off >>= 1) {
        if (t < off) red[t] += red[t + off];
        __syncthreads();
    }
    if (t == 0) hterm[row] = red[0];
}

// ---------------- per-layer: logits, masked softmax, w = skip_p * p[i]; 256 thr ----------------
__global__ void logits_softmax(const float* __restrict__ r, const float* __restrict__ rT,
                               const float* __restrict__ ck, const float* __restrict__ Wd1,
                               const float* __restrict__ hterm, const float* __restrict__ p,
                               const int* __restrict__ code_length, int layer,
                               float* __restrict__ w) {
    __shared__ float ri[H_], ckl[H_], wd[H_];
    __shared__ float part[2][128];
    __shared__ float red[128];
    int t = threadIdx.x;             // 0..255
    int j = t & 127, half = t >> 7;
    int bi = blockIdx.x;
    int b = bi / N_, i = bi % N_;
    ri[t] = r[(size_t)bi * H_ + t];
    ckl[t] = ck[t];
    wd[t] = Wd1[256 + t];
    __syncthreads();
    int len = code_length[b] / T_;
    bool valid = false;
    if (j < N_) {
        if (layer == 0) valid = (j == 1);
        else if (layer == NL_ - 1) valid = (j == len);
        else valid = (j > i && j <= len) || (j == len);
    }
    float acc = 0.0f;
    if (valid) {
        const float* rTb = rT + (size_t)b * H_ * 128 + j;
        int h0 = half * 128;
#pragma unroll 4
        for (int hh = 0; hh < 128; hh++) {
            int h = h0 + hh;
            float v = rTb[(size_t)h * 128] - ri[h] + ckl[h];
            acc = fmaf(fmaxf(v, 0.0f), wd[h], acc);
        }
    }
    part[half][j] = acc;
    __syncthreads();
    float logit = -3.0e38f;
    if (half == 0 && valid) logit = part[0][j] + part[1][j] + hterm[bi];
    if (half == 0) red[j] = logit;
    __syncthreads();
    for (int off = 64; off > 0; off >>= 1) {
        if (t < off) red[t] = fmaxf(red[t], red[t + off]);
        __syncthreads();
    }
    float m = red[0];
    __syncthreads();
    float e = (half == 0 && valid) ? expf(logit - m) : 0.0f;
    if (half == 0) red[j] = e;
    __syncthreads();
    for (int off = 64; off > 0; off >>= 1) {
        if (t < off) red[t] += red[t + off];
        __syncthreads();
    }
    float s = red[0];
    if (half == 0 && j < N_) w[(size_t)bi * N_ + j] = (e / s) * p[bi];
}

// ---------------- per-layer: gated propagation + weighted aggregation; 512 thr ----------------
__global__ void aggregate(const float* __restrict__ q, const float* __restrict__ he,
                          const float* __restrict__ w, const float* __restrict__ ccur,
                          const float* __restrict__ hcur, float* __restrict__ cnxt,
                          float* __restrict__ hnxt, float* __restrict__ pnxt) {
    __shared__ float qj[1024];
    __shared__ float wcol[128];
    __shared__ float red[128];
    __shared__ int vlist[128];
    __shared__ int nv_s;
    __shared__ float wsum_s;
    __shared__ float parts[2][2][H_];
    int t = threadIdx.x;             // 0..511
    int hh = t & 255, half = t >> 8;
    int bj = blockIdx.x;
    int b = bj / N_, j = bj % N_;
    const float* qjp = q + (size_t)bj * 1024;
    qj[t] = qjp[t];
    qj[512 + t] = qjp[512 + t];
    if (t < 128) wcol[t] = (t < N_) ? w[((size_t)b * N_ + t) * N_ + j] : 0.0f;
    __syncthreads();
    if (t < 128) red[t] = wcol[t];
    if (t == 0) {                    // compacted valid-i list (serial, LDS-only, cheap)
        int nv = 0;
        for (int i = 0; i < N_; i++)
            if (wcol[i] != 0.0f) vlist[nv++] = i;
        nv_s = nv;
    }
    __syncthreads();
    for (int off = 64; off > 0; off >>= 1) {
        if (t < off) red[t] += red[t + off];
        __syncthreads();
    }
    if (t == 0) wsum_s = red[0];
    __syncthreads();
    int nv = nv_s;
    float wsum = wsum_s;
    float accc = 0.0f, acch = 0.0f;
    for (int v = half; v < nv; v += 2) {
        int i = vlist[v];
        float wv = wcol[i];
        size_t rowi = (size_t)b * N_ + i;
        if (j > i) {
            const float* qi = q + rowi * 1024;
            const float* hei = he + rowi * 1024;
            float gi = qj[hh] - qi[hh] + hei[hh];
            float gf = qj[256 + hh] - qi[256 + hh] + hei[256 + hh];
            float gg = qj[512 + hh] - qi[512 + hh] + hei[512 + hh];
            float go = qj[768 + hh] - qi[768 + hh] + hei[768 + hh];
            float cc = ccur[rowi * H_ + hh];
            float cp = sigm(gf) * cc + sigm(gi) * tanhf(gg);
            float hp = sigm(go) * tanhf(cp);
            accc = fmaf(wv, cp, accc);
            acch = fmaf(wv, hp, acch);
        } else {
            accc = fmaf(wv, ccur[rowi * H_ + hh], accc);
            acch = fmaf(wv, hcur[rowi * H_ + hh], acch);
        }
    }
    parts[half][0][hh] = accc;
    parts[half][1][hh] = acch;
    __syncthreads();
    if (half == 0) {
        float inv = 1.0f / (wsum + 1e-7f);
        cnxt[(size_t)bj * H_ + hh] = (parts[0][0][hh] + parts[1][0][hh]) * inv;
        hnxt[(size_t)bj * H_ + hh] = (parts[0][1][hh] + parts[1][1][hh]) * inv;
        if (t == 0) pnxt[bj] = wsum;
    }
}

// ---------------- host launcher ----------------

extern "C" void kernel_launch(void* const* d_in, const int* in_sizes, int n_in,
                              void* d_out, int out_size, void* d_ws, size_t ws_size,
                              hipStream_t stream) {
    const int*   code_statements = (const int*)d_in[0];
    const int*   code_length = (const int*)d_in[1];
    const float* embed = (const float*)d_in[2];
    const float* Wx_s = (const float*)d_in[3];
    const float* Wh_s = (const float*)d_in[4];
    const float* b_s  = (const float*)d_in[5];
    const float* W_se = (const float*)d_in[6];
    const float* b_se = (const float*)d_in[7];
    const float* Wx_e = (const float*)d_in[8];
    const float* Wh_e = (const float*)d_in[9];
    const float* b_e  = (const float*)d_in[10];
    const float* W_hk = (const float*)d_in[11];
    const float* b_hk = (const float*)d_in[12];
    const float* W_sd = (const float*)d_in[13];
    const float* b_sd = (const float*)d_in[14];
    const float* W_d1 = (const float*)d_in[15];
    // d_in[16] = b_d1 : constant shift, softmax-invariant -> unused
    const float* init_a = (const float*)d_in[17];
    const float* init_b = (const float*)d_in[18];
    float* out = (float*)d_out;

    float* wsf = (float*)d_ws;
    size_t off = 0;
    auto alloc = [&](size_t n) { float* p = wsf + off; off += n; return p; };
    float* M1 = alloc(256 * 1024);   // W_se @ Wx_e
    float* M2 = alloc(256 * 256);    // W_se @ W_sd
    float* cz = alloc(1024);         // b_se @ Wx_e + b_e
    float* ck = alloc(256);          // b_se @ W_sd + b_sd
    float* xz = alloc((size_t)3072 * 1024);
    float* stmt = alloc(384 * 256);
    float* pref = alloc(388 * 256);
    float* q  = alloc(388 * 1024);
    float* r_ = alloc(388 * 256);
    float* rT = alloc(4 * 256 * 128);
    float* he = alloc(388 * 1024);
    float* hterm = alloc(388);
    float* w  = alloc(388 * 97);
    float* p0 = alloc(388);
    float* p1 = alloc(388);
    float* c0 = alloc(388 * 256);
    float* c1 = alloc(388 * 256);
    float* h0 = alloc(388 * 256);
    float* h1 = alloc(388 * 256);

    // weight prep (all f32)
    gemm_rowwise<<<dim3(4, 256), 256, 0, stream>>>(W_se, Wx_e, nullptr, M1, 256, 1024);
    gemm_rowwise<<<dim3(1, 256), 256, 0, stream>>>(W_se, W_sd, nullptr, M2, 256, 256);
    gemm_rowwise<<<dim3(4, 1), 256, 0, stream>>>(b_se, Wx_e, b_e, cz, 256, 1024);
    gemm_rowwise<<<dim3(1, 1), 256, 0, stream>>>(b_se, W_sd, b_sd, ck, 256, 256);

    // statement encoder
    xz_gemm<<<dim3(384), 1024, 0, stream>>>(code_statements, embed, Wx_s, b_s, xz);
    lstm_rec<<<dim3(192), 1024, 0, stream>>>(xz, Wh_s, stmt);
    cumsum_k<<<dim3(4), 256, 0, stream>>>(stmt, pref);
    qr_gemm<<<dim3(388), 1024, 0, stream>>>(pref, M1, M2, q, r_, rT);
    init_state<<<dim3(388), 256, 0, stream>>>(init_a, init_b, c0, h0, p0);

    // execution layers
    for (int layer = 0; layer < NL_; layer++) {
        bool odd = (layer & 1);
        float* pc = odd ? p1 : p0;
        float* pn = odd ? p0 : p1;
        float* cc = odd ? c1 : c0;
        float* cn = odd ? c0 : c1;
        float* hc = odd ? h1 : h0;
        float* hn = odd ? h0 : h1;
        if (layer == NL_ - 1) hn = out;  // final h goes straight to d_out
        hproj<<<dim3(388), 1024, 0, stream>>>(hc, Wh_e, W_hk, b_hk, W_d1, cz, he, hterm);
        logits_softmax<<<dim3(388), 256, 0, stream>>>(r_, rT, ck, W_d1, hterm, pc,
                                                      code_length, layer, w);
        aggregate<<<dim3(388), 512, 0, stream>>>(q, he, w, cc, hc, cn, hn, pn);
    }
}

// Round 4
// 692.108 us; speedup vs baseline: 1.1551x; 1.1551x over previous
//
#include <hip/hip_runtime.h>
#include <cstddef>

// Problem constants
#define B_   4
#define NS_  96
#define T_   8
#define H_   256
#define N_   97      // NS + 1
#define NL_  6       // NUM_LAYERS
#define R_   388     // B_ * N_

__device__ __forceinline__ float sigm(float x) { return 1.0f / (1.0f + expf(-x)); }

// ---------------- generic: C[m,n] = sum_k A[m,k]*B[k,n] (+bias[n]), K<=256 ----------------
__global__ void gemm_rowwise(const float* __restrict__ A, const float* __restrict__ Bm,
                             const float* __restrict__ bias, float* __restrict__ C,
                             int K, int Nc) {
    __shared__ float a[256];
    int m = blockIdx.y;
    int t = threadIdx.x;
    if (t < K) a[t] = A[m * K + t];
    __syncthreads();
    int n = blockIdx.x * 256 + t;
    if (n < Nc) {
        float acc = bias ? bias[n] : 0.0f;
        for (int k = 0; k < K; k++) acc = fmaf(a[k], Bm[k * Nc + n], acc);
        C[m * Nc + n] = acc;
    }
}

// ---------------- xz = embed[ids] @ Wx_s + b_s   [3072,1024], 8 rows/block ----------------
__global__ void xz_gemm(const int* __restrict__ ids, const float* __restrict__ embed,
                        const float* __restrict__ Wx, const float* __restrict__ bs,
                        float* __restrict__ xz) {
    __shared__ float x[8][H_];
    __shared__ int idx[8];
    int t = threadIdx.x;             // 0..1023
    int r0 = blockIdx.x * 8;
    if (t < 8) idx[t] = ids[r0 + t];
    __syncthreads();
    {
        int r = t >> 7;              // 0..7
        int cb = (t & 127) * 2;
        const float* e = embed + (size_t)idx[r] * H_;
        x[r][cb] = e[cb];
        x[r][cb + 1] = e[cb + 1];
    }
    __syncthreads();
    float acc[8];
    float bv = bs[t];
#pragma unroll
    for (int r = 0; r < 8; r++) acc[r] = bv;
#pragma unroll 4
    for (int k = 0; k < H_; k++) {
        float wv = Wx[k * 1024 + t];
#pragma unroll
        for (int r = 0; r < 8; r++) acc[r] = fmaf(x[r][k], wv, acc[r]);
    }
#pragma unroll
    for (int r = 0; r < 8; r++) xz[(size_t)(r0 + r) * 1024 + t] = acc[r];
}

// ---------------- recurrent LSTM: 2 seqs/block, 2 k-halves, float4 weight loads ----------------
__global__ void lstm_rec(const float* __restrict__ xz, const float* __restrict__ Wh,
                         float* __restrict__ stmt) {
    __shared__ float hb[2][H_];          // current h per seq
    __shared__ float zp[2][2][1024];     // [kgroup][seq][gatecol] partial z (16 KB)
    int t = threadIdx.x;                 // 0..1023
    int kg = t >> 9;                     // k-half: 0 -> k 0..127, 1 -> 128..255
    int sq = (t >> 8) & 1;               // sequence within block
    int c4 = (t & 255) * 4;              // 4 adjacent gate columns
    int gs = t >> 8, ge = t & 255;       // gate ownership (threads t<512)
    int s0 = blockIdx.x * 2;
    float cst = 0.0f;                    // cell state (gate threads only)
    for (int step = 0; step < T_; step++) {
        if (step == 0) {                 // h == 0: z = xz row directly
            if (t < 512) {
                const float* z = xz + ((size_t)(s0 + gs) * T_) * 1024;
                float gi = z[ge], gf = z[256 + ge], gg = z[512 + ge], go = z[768 + ge];
                cst = sigm(gf) * cst + sigm(gi) * tanhf(gg);
                hb[gs][ge] = sigm(go) * tanhf(cst);
            }
            __syncthreads();
        } else {
            const float* xzp = xz + (((size_t)(s0 + sq)) * T_ + step) * 1024 + c4;
            float4 acc;
            if (kg == 0) acc = *(const float4*)xzp;
            else         acc = make_float4(0.f, 0.f, 0.f, 0.f);
            const float* wb = Wh + (size_t)(kg * 128) * 1024 + c4;
            const float* hrow = hb[sq] + kg * 128;
#pragma unroll 8
            for (int k = 0; k < 128; k++) {
                float4 w4 = *(const float4*)(wb + (size_t)k * 1024);
                float hv = hrow[k];
                acc.x = fmaf(hv, w4.x, acc.x);
                acc.y = fmaf(hv, w4.y, acc.y);
                acc.z = fmaf(hv, w4.z, acc.z);
                acc.w = fmaf(hv, w4.w, acc.w);
            }
            *(float4*)&zp[kg][sq][c4] = acc;
            __syncthreads();             // zp complete; all hb reads done
            if (t < 512) {
                float gi = zp[0][gs][ge] + zp[1][gs][ge];
                float gf = zp[0][gs][256 + ge] + zp[1][gs][256 + ge];
                float gg = zp[0][gs][512 + ge] + zp[1][gs][512 + ge];
                float go = zp[0][gs][768 + ge] + zp[1][gs][768 + ge];
                cst = sigm(gf) * cst + sigm(gi) * tanhf(gg);
                hb[gs][ge] = sigm(go) * tanhf(cst);
            }
            __syncthreads();             // hb ready for next step
        }
    }
    if (t < 512) stmt[(size_t)(s0 + gs) * H_ + ge] = hb[gs][ge];
}

// ---------------- prefix sums over statements ----------------
__global__ void cumsum_k(const float* __restrict__ stmt, float* __restrict__ pref) {
    int b = blockIdx.x, t = threadIdx.x;
    float run = 0.0f;
    pref[((size_t)b * N_) * H_ + t] = 0.0f;
    for (int n = 1; n < N_; n++) {
        run += stmt[((size_t)b * NS_ + n - 1) * H_ + t];
        pref[((size_t)b * N_ + n) * H_ + t] = run;
    }
}

// ---------------- q = pref@M1 (4H), r = pref@M2 (H) + rT; 1 row/block, 1024 thr ----------------
__global__ void qr_gemm(const float* __restrict__ pref, const float* __restrict__ M1,
                        const float* __restrict__ M2, float* __restrict__ q,
                        float* __restrict__ r, float* __restrict__ rT) {
    __shared__ float pf[H_];
    int t = threadIdx.x;             // 0..1023
    int row = blockIdx.x;            // 0..387
    if (t < H_) pf[t] = pref[(size_t)row * H_ + t];
    __syncthreads();
    float aq = 0.0f, ar = 0.0f;
#pragma unroll 4
    for (int k = 0; k < H_; k++) {
        float pv = pf[k];
        aq = fmaf(pv, M1[k * 1024 + t], aq);
        if (t < H_) ar = fmaf(pv, M2[k * 256 + t], ar);
    }
    q[(size_t)row * 1024 + t] = aq;
    if (t < H_) {
        r[(size_t)row * H_ + t] = ar;
        int b = row / N_, n = row % N_;
        rT[((size_t)b * H_ + t) * 128 + n] = ar;
    }
}

// ---------------- init c/h/p ----------------
__global__ void init_state(const float* __restrict__ ia, const float* __restrict__ ib,
                           float* __restrict__ c0, float* __restrict__ h0,
                           float* __restrict__ p0) {
    int row = blockIdx.x, t = threadIdx.x;
    size_t idx = (size_t)row * H_ + t;
    c0[idx] = ia[t];
    h0[idx] = ib[t];
    if (t == 0) p0[row] = ((row % N_) == 0) ? 1.0f : 0.0f;
}

// ---------------- per-layer: he[388,1024] = h@Whe + cz, tiled GEMM BM=32 BN=128 ----------------
__global__ void hproj_gemm(const float* __restrict__ h, const float* __restrict__ Whe,
                           const float* __restrict__ cz, float* __restrict__ he) {
    __shared__ float A[H_][36];      // A[k][r], pad 36 -> 16B-aligned rows, 36.9 KB
    int t = threadIdx.x;             // 0..255
    int n0 = blockIdx.x * 128;
    int r0 = blockIdx.y * 32;
#pragma unroll
    for (int it = 0; it < 32; it++) {
        int r = r0 + it;
        A[t][it] = (r < R_) ? h[(size_t)r * H_ + t] : 0.0f;
    }
    __syncthreads();
    int cg = t & 31;                 // cols n0 + 4cg .. +3
    int rg = t >> 5;                 // rows r0 + rg*4 .. +3
    float acc[4][4] = {};
    const float* wp = Whe + n0 + 4 * cg;
#pragma unroll 4
    for (int k = 0; k < H_; k++) {
        float4 w4 = *(const float4*)(wp + (size_t)k * 1024);
        float4 a4 = *(const float4*)&A[k][rg * 4];
        acc[0][0] = fmaf(a4.x, w4.x, acc[0][0]);
        acc[0][1] = fmaf(a4.x, w4.y, acc[0][1]);
        acc[0][2] = fmaf(a4.x, w4.z, acc[0][2]);
        acc[0][3] = fmaf(a4.x, w4.w, acc[0][3]);
        acc[1][0] = fmaf(a4.y, w4.x, acc[1][0]);
        acc[1][1] = fmaf(a4.y, w4.y, acc[1][1]);
        acc[1][2] = fmaf(a4.y, w4.z, acc[1][2]);
        acc[1][3] = fmaf(a4.y, w4.w, acc[1][3]);
        acc[2][0] = fmaf(a4.z, w4.x, acc[2][0]);
        acc[2][1] = fmaf(a4.z, w4.y, acc[2][1]);
        acc[2][2] = fmaf(a4.z, w4.z, acc[2][2]);
        acc[2][3] = fmaf(a4.z, w4.w, acc[2][3]);
        acc[3][0] = fmaf(a4.w, w4.x, acc[3][0]);
        acc[3][1] = fmaf(a4.w, w4.y, acc[3][1]);
        acc[3][2] = fmaf(a4.w, w4.z, acc[3][2]);
        acc[3][3] = fmaf(a4.w, w4.w, acc[3][3]);
    }
    float4 czv = *(const float4*)&cz[n0 + 4 * cg];
#pragma unroll
    for (int rr = 0; rr < 4; rr++) {
        int r = r0 + rg * 4 + rr;
        if (r < R_) {
            float4 o;
            o.x = acc[rr][0] + czv.x;
            o.y = acc[rr][1] + czv.y;
            o.z = acc[rr][2] + czv.z;
            o.w = acc[rr][3] + czv.w;
            *(float4*)&he[(size_t)r * 1024 + n0 + 4 * cg] = o;
        }
    }
}

// ---------------- per-layer: logits, masked softmax, w = skip_p * p[i]; 256 thr ----------------
// NOTE: h_key relu term and b_d1 are constant along j -> cancel in softmax -> omitted.
__global__ void logits_softmax(const float* __restrict__ r, const float* __restrict__ rT,
                               const float* __restrict__ ck, const float* __restrict__ Wd1,
                               const float* __restrict__ p,
                               const int* __restrict__ code_length, int layer,
                               float* __restrict__ w) {
    __shared__ float ri[H_], ckl[H_], wd[H_];
    __shared__ float part[2][128];
    __shared__ float red[128];
    int t = threadIdx.x;             // 0..255
    int j = t & 127, half = t >> 7;
    int bi = blockIdx.x;
    int b = bi / N_, i = bi % N_;
    ri[t] = r[(size_t)bi * H_ + t];
    ckl[t] = ck[t];
    wd[t] = Wd1[256 + t];
    __syncthreads();
    int len = code_length[b] / T_;
    bool valid = false;
    if (j < N_) {
        if (layer == 0) valid = (j == 1);
        else if (layer == NL_ - 1) valid = (j == len);
        else valid = (j > i && j <= len) || (j == len);
    }
    float acc = 0.0f;
    if (valid) {
        const float* rTb = rT + (size_t)b * H_ * 128 + j;
        int h0 = half * 128;
#pragma unroll 4
        for (int hh = 0; hh < 128; hh++) {
            int h = h0 + hh;
            float v = rTb[(size_t)h * 128] - ri[h] + ckl[h];
            acc = fmaf(fmaxf(v, 0.0f), wd[h], acc);
        }
    }
    part[half][j] = acc;
    __syncthreads();
    float logit = -3.0e38f;
    if (half == 0 && valid) logit = part[0][j] + part[1][j];
    if (half == 0) red[j] = logit;
    __syncthreads();
    for (int off = 64; off > 0; off >>= 1) {
        if (t < off) red[t] = fmaxf(red[t], red[t + off]);
        __syncthreads();
    }
    float m = red[0];
    __syncthreads();
    float e = (half == 0 && valid) ? expf(logit - m) : 0.0f;
    if (half == 0) red[j] = e;
    __syncthreads();
    for (int off = 64; off > 0; off >>= 1) {
        if (t < off) red[t] += red[t + off];
        __syncthreads();
    }
    float s = red[0];
    if (half == 0 && j < N_) w[(size_t)bi * N_ + j] = (e / s) * p[bi];
}

// ---------------- per-layer: gated propagation + weighted aggregation; 512 thr ----------------
__global__ void aggregate(const float* __restrict__ q, const float* __restrict__ he,
                          const float* __restrict__ w, const float* __restrict__ ccur,
                          const float* __restrict__ hcur, float* __restrict__ cnxt,
                          float* __restrict__ hnxt, float* __restrict__ pnxt) {
    __shared__ float qj[1024];
    __shared__ float wcol[128];
    __shared__ float red[128];
    __shared__ int vlist[128];
    __shared__ int nv_s;
    __shared__ float wsum_s;
    __shared__ float parts[2][2][H_];
    int t = threadIdx.x;             // 0..511
    int hh = t & 255, half = t >> 8;
    int bj = blockIdx.x;
    int b = bj / N_, j = bj % N_;
    const float* qjp = q + (size_t)bj * 1024;
    qj[t] = qjp[t];
    qj[512 + t] = qjp[512 + t];
    if (t < 128) wcol[t] = (t < N_) ? w[((size_t)b * N_ + t) * N_ + j] : 0.0f;
    __syncthreads();
    if (t < 128) red[t] = wcol[t];
    if (t == 0) {                    // compacted valid-i list
        int nv = 0;
        for (int i = 0; i < N_; i++)
            if (wcol[i] != 0.0f) vlist[nv++] = i;
        nv_s = nv;
    }
    __syncthreads();
    for (int off = 64; off > 0; off >>= 1) {
        if (t < off) red[t] += red[t + off];
        __syncthreads();
    }
    if (t == 0) wsum_s = red[0];
    __syncthreads();
    int nv = nv_s;
    float wsum = wsum_s;
    float accc = 0.0f, acch = 0.0f;
    for (int v = half; v < nv; v += 2) {
        int i = vlist[v];
        float wv = wcol[i];
        size_t rowi = (size_t)b * N_ + i;
        if (j > i) {
            const float* qi = q + rowi * 1024;
            const float* hei = he + rowi * 1024;
            float gi = qj[hh] - qi[hh] + hei[hh];
            float gf = qj[256 + hh] - qi[256 + hh] + hei[256 + hh];
            float gg = qj[512 + hh] - qi[512 + hh] + hei[512 + hh];
            float go = qj[768 + hh] - qi[768 + hh] + hei[768 + hh];
            float cc = ccur[rowi * H_ + hh];
            float cp = sigm(gf) * cc + sigm(gi) * tanhf(gg);
            float hp = sigm(go) * tanhf(cp);
            accc = fmaf(wv, cp, accc);
            acch = fmaf(wv, hp, acch);
        } else {
            accc = fmaf(wv, ccur[rowi * H_ + hh], accc);
            acch = fmaf(wv, hcur[rowi * H_ + hh], acch);
        }
    }
    parts[half][0][hh] = accc;
    parts[half][1][hh] = acch;
    __syncthreads();
    if (half == 0) {
        float inv = 1.0f / (wsum + 1e-7f);
        cnxt[(size_t)bj * H_ + hh] = (parts[0][0][hh] + parts[1][0][hh]) * inv;
        hnxt[(size_t)bj * H_ + hh] = (parts[0][1][hh] + parts[1][1][hh]) * inv;
        if (t == 0) pnxt[bj] = wsum;
    }
}

// ---------------- host launcher ----------------

extern "C" void kernel_launch(void* const* d_in, const int* in_sizes, int n_in,
                              void* d_out, int out_size, void* d_ws, size_t ws_size,
                              hipStream_t stream) {
    const int*   code_statements = (const int*)d_in[0];
    const int*   code_length = (const int*)d_in[1];
    const float* embed = (const float*)d_in[2];
    const float* Wx_s = (const float*)d_in[3];
    const float* Wh_s = (const float*)d_in[4];
    const float* b_s  = (const float*)d_in[5];
    const float* W_se = (const float*)d_in[6];
    const float* b_se = (const float*)d_in[7];
    const float* Wx_e = (const float*)d_in[8];
    const float* Wh_e = (const float*)d_in[9];
    const float* b_e  = (const float*)d_in[10];
    const float* W_sd = (const float*)d_in[13];
    const float* b_sd = (const float*)d_in[14];
    const float* W_d1 = (const float*)d_in[15];
    // d_in[11] W_hk, d_in[12] b_hk, d_in[16] b_d1: softmax-invariant -> unused
    const float* init_a = (const float*)d_in[17];
    const float* init_b = (const float*)d_in[18];
    float* out = (float*)d_out;

    float* wsf = (float*)d_ws;
    size_t off = 0;
    auto alloc = [&](size_t n) { float* p = wsf + off; off += n; return p; };
    float* M1 = alloc(256 * 1024);   // W_se @ Wx_e
    float* M2 = alloc(256 * 256);    // W_se @ W_sd
    float* cz = alloc(1024);         // b_se @ Wx_e + b_e
    float* ck = alloc(256);          // b_se @ W_sd + b_sd
    float* xz = alloc((size_t)3072 * 1024);
    float* stmt = alloc(384 * 256);
    float* pref = alloc(R_ * 256);
    float* q  = alloc(R_ * 1024);
    float* r_ = alloc(R_ * 256);
    float* rT = alloc(4 * 256 * 128);
    float* he = alloc(R_ * 1024);
    float* w  = alloc(R_ * 97);
    float* p0 = alloc(R_);
    float* p1 = alloc(R_);
    float* c0 = alloc(R_ * 256);
    float* c1 = alloc(R_ * 256);
    float* h0 = alloc(R_ * 256);
    float* h1 = alloc(R_ * 256);

    // weight prep (all f32)
    gemm_rowwise<<<dim3(4, 256), 256, 0, stream>>>(W_se, Wx_e, nullptr, M1, 256, 1024);
    gemm_rowwise<<<dim3(1, 256), 256, 0, stream>>>(W_se, W_sd, nullptr, M2, 256, 256);
    gemm_rowwise<<<dim3(4, 1), 256, 0, stream>>>(b_se, Wx_e, b_e, cz, 256, 1024);
    gemm_rowwise<<<dim3(1, 1), 256, 0, stream>>>(b_se, W_sd, b_sd, ck, 256, 256);

    // statement encoder
    xz_gemm<<<dim3(384), 1024, 0, stream>>>(code_statements, embed, Wx_s, b_s, xz);
    lstm_rec<<<dim3(192), 1024, 0, stream>>>(xz, Wh_s, stmt);
    cumsum_k<<<dim3(4), 256, 0, stream>>>(stmt, pref);
    qr_gemm<<<dim3(R_), 1024, 0, stream>>>(pref, M1, M2, q, r_, rT);
    init_state<<<dim3(R_), 256, 0, stream>>>(init_a, init_b, c0, h0, p0);

    // execution layers
    for (int layer = 0; layer < NL_; layer++) {
        bool odd = (layer & 1);
        float* pc = odd ? p1 : p0;
        float* pn = odd ? p0 : p1;
        float* cc = odd ? c1 : c0;
        float* cn = odd ? c0 : c1;
        float* hc = odd ? h1 : h0;
        float* hn = odd ? h0 : h1;
        if (layer == NL_ - 1) hn = out;  // final h straight to d_out
        hproj_gemm<<<dim3(8, 13), 256, 0, stream>>>(hc, Wh_e, cz, he);
        logits_softmax<<<dim3(R_), 256, 0, stream>>>(r_, rT, ck, W_d1, pc,
                                                     code_length, layer, w);
        aggregate<<<dim3(R_), 512, 0, stream>>>(q, he, w, cc, hc, cn, hn, pn);
    }
}

// Round 5
// 649.643 us; speedup vs baseline: 1.2306x; 1.0654x over previous
//
#include <hip/hip_runtime.h>
#include <cstddef>

// Problem constants
#define B_   4
#define NS_  96
#define T_   8
#define H_   256
#define N_   97      // NS + 1
#define NL_  6       // NUM_LAYERS
#define R_   388     // B_ * N_

// fast gates: v_exp_f32 (2^x) + v_rcp_f32
__device__ __forceinline__ float sigm(float x) {
    return __builtin_amdgcn_rcpf(1.0f + __builtin_amdgcn_exp2f(-1.44269504f * x));
}
__device__ __forceinline__ float tanh_f(float x) {
    return 1.0f - 2.0f * __builtin_amdgcn_rcpf(1.0f + __builtin_amdgcn_exp2f(2.88539008f * x));
}

// ---------------- generic: C[m,n] = sum_k A[m,k]*B[k,n] (+bias[n]), K<=256 (tiny prep) ----------------
__global__ void gemm_rowwise(const float* __restrict__ A, const float* __restrict__ Bm,
                             const float* __restrict__ bias, float* __restrict__ C,
                             int K, int Nc) {
    __shared__ float a[256];
    int m = blockIdx.y;
    int t = threadIdx.x;
    if (t < K) a[t] = A[m * K + t];
    __syncthreads();
    int n = blockIdx.x * 256 + t;
    if (n < Nc) {
        float acc = bias ? bias[n] : 0.0f;
        for (int k = 0; k < K; k++) acc = fmaf(a[k], Bm[k * Nc + n], acc);
        C[m * Nc + n] = acc;
    }
}

// ---------------- tiled GEMM: C[R][NC] = A[R][256] @ W[256][NC] (+bias), 16x256 tile ----------------
__global__ void gemm_tiled(const float* __restrict__ A, const float* __restrict__ W,
                           const float* __restrict__ bias, float* __restrict__ C,
                           int R, int NC) {
    __shared__ float As[256][20];    // [k][r], pad 20 -> 16B-aligned quads
    int t = threadIdx.x;             // 0..255
    int n0 = blockIdx.x * 256;
    int r0 = blockIdx.y * 16;
#pragma unroll
    for (int it = 0; it < 16; it++) {
        int r = r0 + it;
        As[t][it] = (r < R) ? A[(size_t)r * 256 + t] : 0.0f;
    }
    __syncthreads();
    int cg = t & 63;                 // 64 col-quads -> cols n0+4cg..+3
    int rg = t >> 6;                 // 4 row-quads -> rows r0+4rg..+3
    float acc[4][4] = {};
    const float* wp = W + n0 + 4 * cg;
#pragma unroll 2
    for (int k = 0; k < 256; k++) {
        float4 w4 = *(const float4*)(wp + (size_t)k * NC);
        float4 a4 = *(const float4*)&As[k][rg * 4];
        acc[0][0] = fmaf(a4.x, w4.x, acc[0][0]);
        acc[0][1] = fmaf(a4.x, w4.y, acc[0][1]);
        acc[0][2] = fmaf(a4.x, w4.z, acc[0][2]);
        acc[0][3] = fmaf(a4.x, w4.w, acc[0][3]);
        acc[1][0] = fmaf(a4.y, w4.x, acc[1][0]);
        acc[1][1] = fmaf(a4.y, w4.y, acc[1][1]);
        acc[1][2] = fmaf(a4.y, w4.z, acc[1][2]);
        acc[1][3] = fmaf(a4.y, w4.w, acc[1][3]);
        acc[2][0] = fmaf(a4.z, w4.x, acc[2][0]);
        acc[2][1] = fmaf(a4.z, w4.y, acc[2][1]);
        acc[2][2] = fmaf(a4.z, w4.z, acc[2][2]);
        acc[2][3] = fmaf(a4.z, w4.w, acc[2][3]);
        acc[3][0] = fmaf(a4.w, w4.x, acc[3][0]);
        acc[3][1] = fmaf(a4.w, w4.y, acc[3][1]);
        acc[3][2] = fmaf(a4.w, w4.z, acc[3][2]);
        acc[3][3] = fmaf(a4.w, w4.w, acc[3][3]);
    }
    float4 bv = bias ? *(const float4*)&bias[n0 + 4 * cg] : make_float4(0.f, 0.f, 0.f, 0.f);
#pragma unroll
    for (int rr = 0; rr < 4; rr++) {
        int r = r0 + rg * 4 + rr;
        if (r < R) {
            float4 o;
            o.x = acc[rr][0] + bv.x;
            o.y = acc[rr][1] + bv.y;
            o.z = acc[rr][2] + bv.z;
            o.w = acc[rr][3] + bv.w;
            *(float4*)&C[(size_t)r * NC + n0 + 4 * cg] = o;
        }
    }
}

// ---------------- xz = embed[ids] @ Wx_s + b_s   [3072,1024], 8 rows/block ----------------
__global__ void xz_gemm(const int* __restrict__ ids, const float* __restrict__ embed,
                        const float* __restrict__ Wx, const float* __restrict__ bs,
                        float* __restrict__ xz) {
    __shared__ float x[8][H_];
    __shared__ int idx[8];
    int t = threadIdx.x;             // 0..1023
    int r0 = blockIdx.x * 8;
    if (t < 8) idx[t] = ids[r0 + t];
    __syncthreads();
    {
        int r = t >> 7;
        int cb = (t & 127) * 2;
        const float* e = embed + (size_t)idx[r] * H_;
        x[r][cb] = e[cb];
        x[r][cb + 1] = e[cb + 1];
    }
    __syncthreads();
    float acc[8];
    float bv = bs[t];
#pragma unroll
    for (int r = 0; r < 8; r++) acc[r] = bv;
#pragma unroll 4
    for (int k = 0; k < H_; k++) {
        float wv = Wx[k * 1024 + t];
#pragma unroll
        for (int r = 0; r < 8; r++) acc[r] = fmaf(x[r][k], wv, acc[r]);
    }
#pragma unroll
    for (int r = 0; r < 8; r++) xz[(size_t)(r0 + r) * 1024 + t] = acc[r];
}

// ---------------- LSTM one step: distributed GEMM, 12 stripes x 16 col-tiles ----------------
// block: 32 seqs x 64 gate-cols (4 gates x 16 h-elements). Wh slice + h stripe in LDS.
__global__ void lstm_step(int step, const float* __restrict__ xz, const float* __restrict__ Wh,
                          float* __restrict__ hbuf, float* __restrict__ cbuf) {
    __shared__ float Wh_s[256][64];  // 64 KB
    __shared__ float h_s[32][260];   // 32.5 KB (pad 260: conflict-free, 16B-aligned)
    __shared__ float zs[32][68];     // 8.5 KB
    int t = threadIdx.x;             // 0..255
    int ct = blockIdx.x;             // col tile 0..15 -> e-range
    int st = blockIdx.y;             // stripe 0..11
    int et0 = ct * 16;
    int s0 = st * 32;
    int sp = t >> 4;                 // 0..15  (seqs sp, sp+16)
    int cq = t & 15;                 // col-quad: gate g=cq>>2, q4=cq&3
    int g = cq >> 2, q4 = cq & 3;
    int gcol = g * 256 + et0 + q4 * 4;

    float4 a0, a1;
    {   // z init = xz slice (x-projection already includes bias)
        const float* x0 = xz + (((size_t)(s0 + sp)) * T_ + step) * 1024 + gcol;
        const float* x1 = xz + (((size_t)(s0 + sp + 16)) * T_ + step) * 1024 + gcol;
        a0 = *(const float4*)x0;
        a1 = *(const float4*)x1;
    }
    if (step > 0) {
        // stage Wh slice: 4096 float4s
#pragma unroll
        for (int m = 0; m < 16; m++) {
            int L = m * 256 + t;
            int k = L >> 4, f = L & 15;
            int gg = f >> 2, qq = f & 3;
            *(float4*)&Wh_s[k][f * 4] = *(const float4*)&Wh[(size_t)k * 1024 + gg * 256 + et0 + qq * 4];
        }
        // stage h stripe: 2048 float4s
#pragma unroll
        for (int m = 0; m < 8; m++) {
            int L = m * 256 + t;
            int seq = L >> 6, c4 = (L & 63) * 4;
            *(float4*)&h_s[seq][c4] = *(const float4*)&hbuf[(size_t)(s0 + seq) * H_ + c4];
        }
        __syncthreads();
#pragma unroll 4
        for (int k = 0; k < 256; k++) {
            float4 w4 = *(const float4*)&Wh_s[k][cq * 4];
            float h0 = h_s[sp][k];
            float h1 = h_s[sp + 16][k];
            a0.x = fmaf(h0, w4.x, a0.x);
            a0.y = fmaf(h0, w4.y, a0.y);
            a0.z = fmaf(h0, w4.z, a0.z);
            a0.w = fmaf(h0, w4.w, a0.w);
            a1.x = fmaf(h1, w4.x, a1.x);
            a1.y = fmaf(h1, w4.y, a1.y);
            a1.z = fmaf(h1, w4.z, a1.z);
            a1.w = fmaf(h1, w4.w, a1.w);
        }
    }
    *(float4*)&zs[sp][cq * 4] = a0;
    *(float4*)&zs[sp + 16][cq * 4] = a1;
    __syncthreads();
    // gates: thread handles (seqA, e) and (seqA+16, e)
    int seqA = t >> 4, e = t & 15;
#pragma unroll
    for (int u = 0; u < 2; u++) {
        int seq = seqA + u * 16;
        float gi = zs[seq][0 * 16 + e];
        float gf = zs[seq][1 * 16 + e];
        float gg = zs[seq][2 * 16 + e];
        float go = zs[seq][3 * 16 + e];
        size_t gidx = (size_t)(s0 + seq) * H_ + et0 + e;
        float cprev = (step > 0) ? cbuf[gidx] : 0.0f;
        float cnew = sigm(gf) * cprev + sigm(gi) * tanh_f(gg);
        cbuf[gidx] = cnew;
        hbuf[gidx] = sigm(go) * tanh_f(cnew);
    }
}

// ---------------- prefix sums over statements ----------------
__global__ void cumsum_k(const float* __restrict__ stmt, float* __restrict__ pref) {
    int b = blockIdx.x, t = threadIdx.x;
    float run = 0.0f;
    pref[((size_t)b * N_) * H_ + t] = 0.0f;
    for (int n = 1; n < N_; n++) {
        run += stmt[((size_t)b * NS_ + n - 1) * H_ + t];
        pref[((size_t)b * N_ + n) * H_ + t] = run;
    }
}

// ---------------- rT[b][h][n] = r[b][n][h] ----------------
__global__ void transpose_rT(const float* __restrict__ r, float* __restrict__ rT) {
    int row = blockIdx.x;            // 0..387
    int t = threadIdx.x;             // 0..255
    int b = row / N_, n = row % N_;
    rT[((size_t)b * H_ + t) * 128 + n] = r[(size_t)row * H_ + t];
}

// ---------------- init c/h/p ----------------
__global__ void init_state(const float* __restrict__ ia, const float* __restrict__ ib,
                           float* __restrict__ c0, float* __restrict__ h0,
                           float* __restrict__ p0) {
    int row = blockIdx.x, t = threadIdx.x;
    size_t idx = (size_t)row * H_ + t;
    c0[idx] = ia[t];
    h0[idx] = ib[t];
    if (t == 0) p0[row] = ((row % N_) == 0) ? 1.0f : 0.0f;
}

// ---------------- per-layer: logits, masked softmax, w = skip_p * p[i]; 1024 thr ----------------
// h_key relu term and b_d1 are constant along j -> cancel in softmax -> omitted.
__global__ void logits_softmax(const float* __restrict__ r, const float* __restrict__ rT,
                               const float* __restrict__ ck, const float* __restrict__ Wd1,
                               const float* __restrict__ p,
                               const int* __restrict__ code_length, int layer,
                               float* __restrict__ w) {
    __shared__ float ri[H_], ckl[H_], wd[H_];
    __shared__ float part[8][128];
    __shared__ float red[128];
    int t = threadIdx.x;             // 0..1023
    int j = t & 127, half = t >> 7;  // 8 h-splits
    int bi = blockIdx.x;
    int b = bi / N_, i = bi % N_;
    if (t < H_) {
        ri[t] = r[(size_t)bi * H_ + t];
        ckl[t] = ck[t];
        wd[t] = Wd1[256 + t];
    }
    __syncthreads();
    int len = code_length[b] / T_;
    bool valid = false;
    if (j < N_) {
        if (layer == 0) valid = (j == 1);
        else if (layer == NL_ - 1) valid = (j == len);
        else valid = (j > i && j <= len) || (j == len);
    }
    float acc = 0.0f;
    if (valid) {
        const float* rTb = rT + (size_t)b * H_ * 128 + j;
        int h0 = half * 32;
#pragma unroll 4
        for (int hh = 0; hh < 32; hh++) {
            int h = h0 + hh;
            float v = rTb[(size_t)h * 128] - ri[h] + ckl[h];
            acc = fmaf(fmaxf(v, 0.0f), wd[h], acc);
        }
    }
    part[half][j] = acc;
    __syncthreads();
    float logit = -3.0e38f;
    if (t < 128) {
        if (valid) {
            logit = part[0][j] + part[1][j] + part[2][j] + part[3][j]
                  + part[4][j] + part[5][j] + part[6][j] + part[7][j];
        }
        red[j] = logit;
    }
    __syncthreads();
    for (int off = 64; off > 0; off >>= 1) {
        if (t < off) red[t] = fmaxf(red[t], red[t + off]);
        __syncthreads();
    }
    float m = red[0];
    __syncthreads();
    float e = (t < 128 && valid) ? __builtin_amdgcn_exp2f(1.44269504f * (logit - m)) : 0.0f;
    if (t < 128) red[j] = e;
    __syncthreads();
    for (int off = 64; off > 0; off >>= 1) {
        if (t < off) red[t] += red[t + off];
        __syncthreads();
    }
    float s = red[0];
    if (t < 128 && j < N_) w[(size_t)bi * N_ + j] = (e / s) * p[bi];
}

// ---------------- per-layer: gated propagation + weighted aggregation; 1024 thr ----------------
__global__ void aggregate(const float* __restrict__ q, const float* __restrict__ he,
                          const float* __restrict__ w, const float* __restrict__ ccur,
                          const float* __restrict__ hcur, float* __restrict__ cnxt,
                          float* __restrict__ hnxt, float* __restrict__ pnxt) {
    __shared__ float qj[1024];
    __shared__ float wcol[128];
    __shared__ float red[128];
    __shared__ int vlist[128];
    __shared__ int nv_s;
    __shared__ float wsum_s;
    __shared__ float parts[4][2][H_];
    int t = threadIdx.x;             // 0..1023
    int hh = t & 255, vs = t >> 8;   // 4 i-splits
    int bj = blockIdx.x;
    int b = bj / N_, j = bj % N_;
    qj[t] = q[(size_t)bj * 1024 + t];
    if (t < 128) wcol[t] = (t < N_) ? w[((size_t)b * N_ + t) * N_ + j] : 0.0f;
    __syncthreads();
    if (t < 128) red[t] = wcol[t];
    if (t == 0) {                    // compacted valid-i list
        int nv = 0;
        for (int i = 0; i < N_; i++)
            if (wcol[i] != 0.0f) vlist[nv++] = i;
        nv_s = nv;
    }
    __syncthreads();
    for (int off = 64; off > 0; off >>= 1) {
        if (t < off) red[t] += red[t + off];
        __syncthreads();
    }
    if (t == 0) wsum_s = red[0];
    __syncthreads();
    int nv = nv_s;
    float wsum = wsum_s;
    float accc = 0.0f, acch = 0.0f;
    for (int v = vs; v < nv; v += 4) {
        int i = vlist[v];
        float wv = wcol[i];
        size_t rowi = (size_t)b * N_ + i;
        if (j > i) {
            const float* qi = q + rowi * 1024;
            const float* hei = he + rowi * 1024;
            float gi = qj[hh] - qi[hh] + hei[hh];
            float gf = qj[256 + hh] - qi[256 + hh] + hei[256 + hh];
            float gg = qj[512 + hh] - qi[512 + hh] + hei[512 + hh];
            float go = qj[768 + hh] - qi[768 + hh] + hei[768 + hh];
            float cc = ccur[rowi * H_ + hh];
            float cp = sigm(gf) * cc + sigm(gi) * tanh_f(gg);
            float hp = sigm(go) * tanh_f(cp);
            accc = fmaf(wv, cp, accc);
            acch = fmaf(wv, hp, acch);
        } else {
            accc = fmaf(wv, ccur[rowi * H_ + hh], accc);
            acch = fmaf(wv, hcur[rowi * H_ + hh], acch);
        }
    }
    parts[vs][0][hh] = accc;
    parts[vs][1][hh] = acch;
    __syncthreads();
    if (t < 256) {
        float inv = __builtin_amdgcn_rcpf(wsum + 1e-7f);
        float cs = parts[0][0][hh] + parts[1][0][hh] + parts[2][0][hh] + parts[3][0][hh];
        float hs = parts[0][1][hh] + parts[1][1][hh] + parts[2][1][hh] + parts[3][1][hh];
        cnxt[(size_t)bj * H_ + hh] = cs * inv;
        hnxt[(size_t)bj * H_ + hh] = hs * inv;
        if (t == 0) pnxt[bj] = wsum;
    }
}

// ---------------- host launcher ----------------

extern "C" void kernel_launch(void* const* d_in, const int* in_sizes, int n_in,
                              void* d_out, int out_size, void* d_ws, size_t ws_size,
                              hipStream_t stream) {
    const int*   code_statements = (const int*)d_in[0];
    const int*   code_length = (const int*)d_in[1];
    const float* embed = (const float*)d_in[2];
    const float* Wx_s = (const float*)d_in[3];
    const float* Wh_s = (const float*)d_in[4];
    const float* b_s  = (const float*)d_in[5];
    const float* W_se = (const float*)d_in[6];
    const float* b_se = (const float*)d_in[7];
    const float* Wx_e = (const float*)d_in[8];
    const float* Wh_e = (const float*)d_in[9];
    const float* b_e  = (const float*)d_in[10];
    const float* W_sd = (const float*)d_in[13];
    const float* b_sd = (const float*)d_in[14];
    const float* W_d1 = (const float*)d_in[15];
    // d_in[11] W_hk, d_in[12] b_hk, d_in[16] b_d1: softmax-invariant -> unused
    const float* init_a = (const float*)d_in[17];
    const float* init_b = (const float*)d_in[18];
    float* out = (float*)d_out;

    float* wsf = (float*)d_ws;
    size_t off = 0;
    auto alloc = [&](size_t n) { float* p = wsf + off; off += n; return p; };
    float* M1 = alloc(256 * 1024);   // W_se @ Wx_e
    float* M2 = alloc(256 * 256);    // W_se @ W_sd
    float* cz = alloc(1024);         // b_se @ Wx_e + b_e
    float* ck = alloc(256);          // b_se @ W_sd + b_sd
    float* xz = alloc((size_t)3072 * 1024);
    float* stmt = alloc(384 * 256);  // doubles as LSTM hbuf
    float* cls = alloc(384 * 256);   // LSTM cell state
    float* pref = alloc(R_ * 256);
    float* q  = alloc(R_ * 1024);
    float* r_ = alloc(R_ * 256);
    float* rT = alloc(4 * 256 * 128);
    float* he = alloc(R_ * 1024);
    float* w  = alloc(R_ * 97);
    float* p0 = alloc(R_);
    float* p1 = alloc(R_);
    float* c0 = alloc(R_ * 256);
    float* c1 = alloc(R_ * 256);
    float* h0 = alloc(R_ * 256);
    float* h1 = alloc(R_ * 256);

    // weight prep (tiny)
    gemm_rowwise<<<dim3(4, 256), 256, 0, stream>>>(W_se, Wx_e, nullptr, M1, 256, 1024);
    gemm_rowwise<<<dim3(1, 256), 256, 0, stream>>>(W_se, W_sd, nullptr, M2, 256, 256);
    gemm_rowwise<<<dim3(4, 1), 256, 0, stream>>>(b_se, Wx_e, b_e, cz, 256, 1024);
    gemm_rowwise<<<dim3(1, 1), 256, 0, stream>>>(b_se, W_sd, b_sd, ck, 256, 256);

    // statement encoder
    xz_gemm<<<dim3(384), 1024, 0, stream>>>(code_statements, embed, Wx_s, b_s, xz);
    for (int step = 0; step < T_; step++)
        lstm_step<<<dim3(16, 12), 256, 0, stream>>>(step, xz, Wh_s, stmt, cls);
    cumsum_k<<<dim3(4), 256, 0, stream>>>(stmt, pref);
    gemm_tiled<<<dim3(4, 25), 256, 0, stream>>>(pref, M1, nullptr, q, R_, 1024);
    gemm_tiled<<<dim3(1, 25), 256, 0, stream>>>(pref, M2, nullptr, r_, R_, 256);
    transpose_rT<<<dim3(R_), 256, 0, stream>>>(r_, rT);
    init_state<<<dim3(R_), 256, 0, stream>>>(init_a, init_b, c0, h0, p0);

    // execution layers
    for (int layer = 0; layer < NL_; layer++) {
        bool odd = (layer & 1);
        float* pc = odd ? p1 : p0;
        float* pn = odd ? p0 : p1;
        float* cc = odd ? c1 : c0;
        float* cn = odd ? c0 : c1;
        float* hc = odd ? h1 : h0;
        float* hn = odd ? h0 : h1;
        if (layer == NL_ - 1) hn = out;  // final h straight to d_out
        gemm_tiled<<<dim3(4, 25), 256, 0, stream>>>(hc, Wh_e, cz, he, R_, 1024);
        logits_softmax<<<dim3(R_), 1024, 0, stream>>>(r_, rT, ck, W_d1, pc,
                                                      code_length, layer, w);
        aggregate<<<dim3(R_), 1024, 0, stream>>>(q, he, w, cc, hc, cn, hn, pn);
    }
}

// Round 6
// 495.178 us; speedup vs baseline: 1.6145x; 1.3119x over previous
//
#include <hip/hip_runtime.h>
#include <cstddef>

// Problem constants
#define B_   4
#define NS_  96
#define T_   8
#define H_   256
#define N_   97      // NS + 1
#define NL_  6       // NUM_LAYERS
#define R_   388     // B_ * N_

// fast gates: v_exp_f32 (2^x) + v_rcp_f32
__device__ __forceinline__ float sigm(float x) {
    return __builtin_amdgcn_rcpf(1.0f + __builtin_amdgcn_exp2f(-1.44269504f * x));
}
__device__ __forceinline__ float tanh_f(float x) {
    return 1.0f - 2.0f * __builtin_amdgcn_rcpf(1.0f + __builtin_amdgcn_exp2f(2.88539008f * x));
}

// ---------------- LDS-staged GEMM: C[R,NC] = A[R,256] @ W[256,NC] (+bias) ----------------
// 32x32 tile, 256 thr, 2x2 micro-tile. Optional embed-gather for A rows (ids != nullptr).
// k-loop touches LDS only; staging loads are all independent (one latency round).
__global__ __launch_bounds__(256) void gemm_lds(const float* __restrict__ A,
        const int* __restrict__ ids, const float* __restrict__ embed,
        const float* __restrict__ W, const float* __restrict__ bias,
        float* __restrict__ C, int R, int NC) {
    __shared__ float Ws[256][36];    // pad 36: 16B-aligned rows, conflict-light
    __shared__ float As[32][260];    // row-major, pad 260
    int t = threadIdx.x;
    int n0 = blockIdx.x * 32;
    int r0 = blockIdx.y * 32;
    // stage W tile 256x32 (8 float4 per thread)
    {
        const float* wp = W + n0;
#pragma unroll
        for (int m = 0; m < 8; m++) {
            int L = m * 256 + t;
            int k = L >> 3, q = L & 7;
            *(float4*)&Ws[k][q * 4] = *(const float4*)(wp + (size_t)k * NC + q * 4);
        }
    }
    // stage A tile 32x256 (8 float4 per thread), optional gather
    {
#pragma unroll
        for (int m = 0; m < 8; m++) {
            int L = m * 256 + t;
            int r = L >> 6, c4 = (L & 63) * 4;
            int rr = r0 + r;
            float4 v = make_float4(0.f, 0.f, 0.f, 0.f);
            if (rr < R) {
                const float* ap = ids ? (embed + (size_t)ids[rr] * 256)
                                      : (A + (size_t)rr * 256);
                v = *(const float4*)(ap + c4);
            }
            *(float4*)&As[r][c4] = v;
        }
    }
    __syncthreads();
    int rg = t >> 4, cg = t & 15;
    int ra = 2 * rg, rb = ra + 1;
    float acc00 = 0.f, acc01 = 0.f, acc10 = 0.f, acc11 = 0.f;
#pragma unroll 8
    for (int k = 0; k < 256; k++) {
        float2 w2 = *(const float2*)&Ws[k][2 * cg];
        float a0 = As[ra][k];
        float a1 = As[rb][k];
        acc00 = fmaf(a0, w2.x, acc00);
        acc01 = fmaf(a0, w2.y, acc01);
        acc10 = fmaf(a1, w2.x, acc10);
        acc11 = fmaf(a1, w2.y, acc11);
    }
    float2 bv = make_float2(0.f, 0.f);
    if (bias) bv = *(const float2*)&bias[n0 + 2 * cg];
    if (r0 + ra < R) {
        float2 o; o.x = acc00 + bv.x; o.y = acc01 + bv.y;
        *(float2*)&C[(size_t)(r0 + ra) * NC + n0 + 2 * cg] = o;
    }
    if (r0 + rb < R) {
        float2 o; o.x = acc10 + bv.x; o.y = acc11 + bv.y;
        *(float2*)&C[(size_t)(r0 + rb) * NC + n0 + 2 * cg] = o;
    }
}

// ---------------- tiny bias prep: cz[1024] = b_se@Wx_e + b_e ; ck[256] = b_se@W_sd + b_sd ----------------
__global__ void bias_prep(const float* __restrict__ b_se, const float* __restrict__ Wx_e,
                          const float* __restrict__ b_e, const float* __restrict__ W_sd,
                          const float* __restrict__ b_sd, float* __restrict__ cz,
                          float* __restrict__ ck) {
    __shared__ float a[256];
    int t = threadIdx.x;
    int n = blockIdx.x * 256 + t;    // 0..1279
    a[t] = b_se[t];
    __syncthreads();
    if (n < 1024) {
        float acc = b_e[n];
        for (int k = 0; k < 256; k++) acc = fmaf(a[k], Wx_e[k * 1024 + n], acc);
        cz[n] = acc;
    } else {
        int m = n - 1024;
        float acc = b_sd[m];
        for (int k = 0; k < 256; k++) acc = fmaf(a[k], W_sd[k * 256 + m], acc);
        ck[m] = acc;
    }
}

// ---------------- LSTM one step: distributed GEMM, 12 stripes x 16 col-tiles ----------------
__global__ void lstm_step(int step, const float* __restrict__ xz, const float* __restrict__ Wh,
                          float* __restrict__ hbuf, float* __restrict__ cbuf) {
    __shared__ float Wh_s[256][64];  // 64 KB
    __shared__ float h_s[32][260];
    __shared__ float zs[32][68];
    int t = threadIdx.x;             // 0..255
    int ct = blockIdx.x;             // col tile 0..15
    int st = blockIdx.y;             // stripe 0..11
    int et0 = ct * 16;
    int s0 = st * 32;
    int sp = t >> 4;
    int cq = t & 15;
    int g = cq >> 2, q4 = cq & 3;
    int gcol = g * 256 + et0 + q4 * 4;

    float4 a0, a1;
    {
        const float* x0 = xz + (((size_t)(s0 + sp)) * T_ + step) * 1024 + gcol;
        const float* x1 = xz + (((size_t)(s0 + sp + 16)) * T_ + step) * 1024 + gcol;
        a0 = *(const float4*)x0;
        a1 = *(const float4*)x1;
    }
    if (step > 0) {
#pragma unroll
        for (int m = 0; m < 16; m++) {
            int L = m * 256 + t;
            int k = L >> 4, f = L & 15;
            int gg = f >> 2, qq = f & 3;
            *(float4*)&Wh_s[k][f * 4] = *(const float4*)&Wh[(size_t)k * 1024 + gg * 256 + et0 + qq * 4];
        }
#pragma unroll
        for (int m = 0; m < 8; m++) {
            int L = m * 256 + t;
            int seq = L >> 6, c4 = (L & 63) * 4;
            *(float4*)&h_s[seq][c4] = *(const float4*)&hbuf[(size_t)(s0 + seq) * H_ + c4];
        }
        __syncthreads();
#pragma unroll 4
        for (int k = 0; k < 256; k++) {
            float4 w4 = *(const float4*)&Wh_s[k][cq * 4];
            float h0 = h_s[sp][k];
            float h1 = h_s[sp + 16][k];
            a0.x = fmaf(h0, w4.x, a0.x);
            a0.y = fmaf(h0, w4.y, a0.y);
            a0.z = fmaf(h0, w4.z, a0.z);
            a0.w = fmaf(h0, w4.w, a0.w);
            a1.x = fmaf(h1, w4.x, a1.x);
            a1.y = fmaf(h1, w4.y, a1.y);
            a1.z = fmaf(h1, w4.z, a1.z);
            a1.w = fmaf(h1, w4.w, a1.w);
        }
    }
    *(float4*)&zs[sp][cq * 4] = a0;
    *(float4*)&zs[sp + 16][cq * 4] = a1;
    __syncthreads();
    int seqA = t >> 4, e = t & 15;
#pragma unroll
    for (int u = 0; u < 2; u++) {
        int seq = seqA + u * 16;
        float gi = zs[seq][0 * 16 + e];
        float gf = zs[seq][1 * 16 + e];
        float gg = zs[seq][2 * 16 + e];
        float go = zs[seq][3 * 16 + e];
        size_t gidx = (size_t)(s0 + seq) * H_ + et0 + e;
        float cprev = (step > 0) ? cbuf[gidx] : 0.0f;
        float cnew = sigm(gf) * cprev + sigm(gi) * tanh_f(gg);
        cbuf[gidx] = cnew;
        hbuf[gidx] = sigm(go) * tanh_f(cnew);
    }
}

// ---------------- prefix sums over statements ----------------
__global__ void cumsum_k(const float* __restrict__ stmt, float* __restrict__ pref) {
    int b = blockIdx.x, t = threadIdx.x;
    float run = 0.0f;
    pref[((size_t)b * N_) * H_ + t] = 0.0f;
    for (int n = 1; n < N_; n++) {
        run += stmt[((size_t)b * NS_ + n - 1) * H_ + t];
        pref[((size_t)b * N_ + n) * H_ + t] = run;
    }
}

// ---------------- rT[b][h][n] = r[b][n][h] ----------------
__global__ void transpose_rT(const float* __restrict__ r, float* __restrict__ rT) {
    int row = blockIdx.x;            // 0..387
    int t = threadIdx.x;             // 0..255
    int b = row / N_, n = row % N_;
    rT[((size_t)b * H_ + t) * 128 + n] = r[(size_t)row * H_ + t];
}

// ---------------- init c/h/p ----------------
__global__ void init_state(const float* __restrict__ ia, const float* __restrict__ ib,
                           float* __restrict__ c0, float* __restrict__ h0,
                           float* __restrict__ p0) {
    int row = blockIdx.x, t = threadIdx.x;
    size_t idx = (size_t)row * H_ + t;
    c0[idx] = ia[t];
    h0[idx] = ib[t];
    if (t == 0) p0[row] = ((row % N_) == 0) ? 1.0f : 0.0f;
}

// ---------------- per-layer: logits, masked softmax, w = skip_p * p[i]; 1024 thr ----------------
// h_key relu term and b_d1 are constant along j -> cancel in softmax -> omitted.
__global__ void logits_softmax(const float* __restrict__ r, const float* __restrict__ rT,
                               const float* __restrict__ ck, const float* __restrict__ Wd1,
                               const float* __restrict__ p,
                               const int* __restrict__ code_length, int layer,
                               float* __restrict__ w) {
    __shared__ float ri[H_], ckl[H_], wd[H_];
    __shared__ float part[8][128];
    __shared__ float red[128];
    int t = threadIdx.x;             // 0..1023
    int j = t & 127, half = t >> 7;  // 8 h-splits
    int bi = blockIdx.x;
    int b = bi / N_, i = bi % N_;
    if (t < H_) {
        ri[t] = r[(size_t)bi * H_ + t];
        ckl[t] = ck[t];
        wd[t] = Wd1[256 + t];
    }
    __syncthreads();
    int len = code_length[b] / T_;
    bool valid = false;
    if (j < N_) {
        if (layer == 0) valid = (j == 1);
        else if (layer == NL_ - 1) valid = (j == len);
        else valid = (j > i && j <= len) || (j == len);
    }
    float acc = 0.0f;
    if (valid) {
        const float* rTb = rT + (size_t)b * H_ * 128 + j;
        int h0 = half * 32;
#pragma unroll 4
        for (int hh = 0; hh < 32; hh++) {
            int h = h0 + hh;
            float v = rTb[(size_t)h * 128] - ri[h] + ckl[h];
            acc = fmaf(fmaxf(v, 0.0f), wd[h], acc);
        }
    }
    part[half][j] = acc;
    __syncthreads();
    float logit = -3.0e38f;
    if (t < 128) {
        if (valid) {
            logit = part[0][j] + part[1][j] + part[2][j] + part[3][j]
                  + part[4][j] + part[5][j] + part[6][j] + part[7][j];
        }
        red[j] = logit;
    }
    __syncthreads();
    for (int off = 64; off > 0; off >>= 1) {
        if (t < off) red[t] = fmaxf(red[t], red[t + off]);
        __syncthreads();
    }
    float m = red[0];
    __syncthreads();
    float e = (t < 128 && valid) ? __builtin_amdgcn_exp2f(1.44269504f * (logit - m)) : 0.0f;
    if (t < 128) red[j] = e;
    __syncthreads();
    for (int off = 64; off > 0; off >>= 1) {
        if (t < off) red[t] += red[t + off];
        __syncthreads();
    }
    float s = red[0];
    if (t < 128 && j < N_) w[(size_t)bi * N_ + j] = (e / s) * p[bi];
}

// ---------------- per-layer: gated propagation + weighted aggregation; 1024 thr ----------------
__global__ void aggregate(const float* __restrict__ q, const float* __restrict__ he,
                          const float* __restrict__ w, const float* __restrict__ ccur,
                          const float* __restrict__ hcur, float* __restrict__ cnxt,
                          float* __restrict__ hnxt, float* __restrict__ pnxt) {
    __shared__ float qj[1024];
    __shared__ float wcol[128];
    __shared__ float red[128];
    __shared__ int vlist[128];
    __shared__ int nv_s;
    __shared__ float wsum_s;
    __shared__ float parts[4][2][H_];
    int t = threadIdx.x;             // 0..1023
    int hh = t & 255, vs = t >> 8;   // 4 i-splits
    int bj = blockIdx.x;
    int b = bj / N_, j = bj % N_;
    qj[t] = q[(size_t)bj * 1024 + t];
    if (t < 128) wcol[t] = (t < N_) ? w[((size_t)b * N_ + t) * N_ + j] : 0.0f;
    __syncthreads();
    if (t < 128) red[t] = wcol[t];
    if (t == 0) {
        int nv = 0;
        for (int i = 0; i < N_; i++)
            if (wcol[i] != 0.0f) vlist[nv++] = i;
        nv_s = nv;
    }
    __syncthreads();
    for (int off = 64; off > 0; off >>= 1) {
        if (t < off) red[t] += red[t + off];
        __syncthreads();
    }
    if (t == 0) wsum_s = red[0];
    __syncthreads();
    int nv = nv_s;
    float wsum = wsum_s;
    float accc = 0.0f, acch = 0.0f;
    for (int v = vs; v < nv; v += 4) {
        int i = vlist[v];
        float wv = wcol[i];
        size_t rowi = (size_t)b * N_ + i;
        if (j > i) {
            const float* qi = q + rowi * 1024;
            const float* hei = he + rowi * 1024;
            float gi = qj[hh] - qi[hh] + hei[hh];
            float gf = qj[256 + hh] - qi[256 + hh] + hei[256 + hh];
            float gg = qj[512 + hh] - qi[512 + hh] + hei[512 + hh];
            float go = qj[768 + hh] - qi[768 + hh] + hei[768 + hh];
            float cc = ccur[rowi * H_ + hh];
            float cp = sigm(gf) * cc + sigm(gi) * tanh_f(gg);
            float hp = sigm(go) * tanh_f(cp);
            accc = fmaf(wv, cp, accc);
            acch = fmaf(wv, hp, acch);
        } else {
            accc = fmaf(wv, ccur[rowi * H_ + hh], accc);
            acch = fmaf(wv, hcur[rowi * H_ + hh], acch);
        }
    }
    parts[vs][0][hh] = accc;
    parts[vs][1][hh] = acch;
    __syncthreads();
    if (t < 256) {
        float inv = __builtin_amdgcn_rcpf(wsum + 1e-7f);
        float cs = parts[0][0][hh] + parts[1][0][hh] + parts[2][0][hh] + parts[3][0][hh];
        float hs = parts[0][1][hh] + parts[1][1][hh] + parts[2][1][hh] + parts[3][1][hh];
        cnxt[(size_t)bj * H_ + hh] = cs * inv;
        hnxt[(size_t)bj * H_ + hh] = hs * inv;
        if (t == 0) pnxt[bj] = wsum;
    }
}

// ---------------- host launcher ----------------

extern "C" void kernel_launch(void* const* d_in, const int* in_sizes, int n_in,
                              void* d_out, int out_size, void* d_ws, size_t ws_size,
                              hipStream_t stream) {
    const int*   code_statements = (const int*)d_in[0];
    const int*   code_length = (const int*)d_in[1];
    const float* embed = (const float*)d_in[2];
    const float* Wx_s = (const float*)d_in[3];
    const float* Wh_s = (const float*)d_in[4];
    const float* b_s  = (const float*)d_in[5];
    const float* W_se = (const float*)d_in[6];
    const float* b_se = (const float*)d_in[7];
    const float* Wx_e = (const float*)d_in[8];
    const float* Wh_e = (const float*)d_in[9];
    const float* b_e  = (const float*)d_in[10];
    const float* W_sd = (const float*)d_in[13];
    const float* b_sd = (const float*)d_in[14];
    const float* W_d1 = (const float*)d_in[15];
    // d_in[11] W_hk, d_in[12] b_hk, d_in[16] b_d1: softmax-invariant -> unused
    const float* init_a = (const float*)d_in[17];
    const float* init_b = (const float*)d_in[18];
    float* out = (float*)d_out;

    float* wsf = (float*)d_ws;
    size_t off = 0;
    auto alloc = [&](size_t n) { float* p = wsf + off; off += n; return p; };
    float* M1 = alloc(256 * 1024);   // W_se @ Wx_e
    float* M2 = alloc(256 * 256);    // W_se @ W_sd
    float* cz = alloc(1024);         // b_se @ Wx_e + b_e
    float* ck = alloc(256);          // b_se @ W_sd + b_sd
    float* xz = alloc((size_t)3072 * 1024);
    float* stmt = alloc(384 * 256);  // doubles as LSTM hbuf
    float* cls = alloc(384 * 256);   // LSTM cell state
    float* pref = alloc(R_ * 256);
    float* q  = alloc(R_ * 1024);
    float* r_ = alloc(R_ * 256);
    float* rT = alloc(4 * 256 * 128);
    float* he = alloc(R_ * 1024);
    float* w  = alloc(R_ * 97);
    float* p0 = alloc(R_);
    float* p1 = alloc(R_);
    float* c0 = alloc(R_ * 256);
    float* c1 = alloc(R_ * 256);
    float* h0 = alloc(R_ * 256);
    float* h1 = alloc(R_ * 256);

    // weight prep
    gemm_lds<<<dim3(32, 8), 256, 0, stream>>>(W_se, nullptr, nullptr, Wx_e, nullptr,
                                              M1, 256, 1024);
    gemm_lds<<<dim3(8, 8), 256, 0, stream>>>(W_se, nullptr, nullptr, W_sd, nullptr,
                                             M2, 256, 256);
    bias_prep<<<dim3(5), 256, 0, stream>>>(b_se, Wx_e, b_e, W_sd, b_sd, cz, ck);

    // statement encoder: xz = embed[ids] @ Wx_s + b_s (gathered A)
    gemm_lds<<<dim3(32, 96), 256, 0, stream>>>(nullptr, code_statements, embed, Wx_s, b_s,
                                               xz, 3072, 1024);
    for (int step = 0; step < T_; step++)
        lstm_step<<<dim3(16, 12), 256, 0, stream>>>(step, xz, Wh_s, stmt, cls);
    cumsum_k<<<dim3(4), 256, 0, stream>>>(stmt, pref);
    gemm_lds<<<dim3(32, 13), 256, 0, stream>>>(pref, nullptr, nullptr, M1, nullptr,
                                               q, R_, 1024);
    gemm_lds<<<dim3(8, 13), 256, 0, stream>>>(pref, nullptr, nullptr, M2, nullptr,
                                              r_, R_, 256);
    transpose_rT<<<dim3(R_), 256, 0, stream>>>(r_, rT);
    init_state<<<dim3(R_), 256, 0, stream>>>(init_a, init_b, c0, h0, p0);

    // execution layers
    for (int layer = 0; layer < NL_; layer++) {
        bool odd = (layer & 1);
        float* pc = odd ? p1 : p0;
        float* pn = odd ? p0 : p1;
        float* cc = odd ? c1 : c0;
        float* cn = odd ? c0 : c1;
        float* hc = odd ? h1 : h0;
        float* hn = odd ? h0 : h1;
        if (layer == NL_ - 1) hn = out;  // final h straight to d_out
        gemm_lds<<<dim3(32, 13), 256, 0, stream>>>(hc, nullptr, nullptr, Wh_e, cz,
                                                   he, R_, 1024);
        logits_softmax<<<dim3(R_), 1024, 0, stream>>>(r_, rT, ck, W_d1, pc,
                                                      code_length, layer, w);
        aggregate<<<dim3(R_), 1024, 0, stream>>>(q, he, w, cc, hc, cn, hn, pn);
    }
}